// Round 2
// baseline (449.111 us; speedup 1.0000x reference)
//
#include <hip/hip_runtime.h>
#include <math.h>

// Problem: B=4096, T=256, D=64
//   mats[t] = expm(kernel * time[t])            (T x D x D)
//   out[b,t,i] = sum_j mats[t,i,j] * x0[b,j]    x0 = inputs[:,0,:]
//
// SINGLE fused kernel, one WG per t (256 WGs = 1/CU):
//   Phase A: scaling-and-squaring + Taylor expm in fp32 LDS (as before, but
//            THETA=1.0 & MTERMS=9 — truncation ~3e-7 rel, 25x below the
//            bf16-split noise floor, saves ~2 matmuls + 1 transpose per WG).
//   Phase B: per-wave bf16 hi/lo split of mats into register fragments, then
//            stream all 4096 b-rows: load x0 fp32 straight from `inputs`
//            (1 MB hot set, L2-resident), split in-register, 3-product MFMA,
//            float4 stores. No workspace, no second launch, no mats
//            round-trip; split VALU cost hides under the write-BW phase.

#define TT 256
#define DD 64
#define BB 4096
#define S1 68           // fp32 LDS row stride (words) for expm
#define THETA 1.0f
#define MTERMS 9

typedef __attribute__((ext_vector_type(8))) short short8;
typedef __attribute__((ext_vector_type(4))) float f32x4;

// split fp32 into bf16 hi (RN) + bf16 lo (trunc of residual); x ~ hi+lo, |eps|<~2^-17|x|
__device__ __forceinline__ void bf16_split(float x, unsigned short& hi, unsigned short& lo) {
    union { float f; unsigned int u; } a; a.f = x;
    unsigned int r = (a.u + 0x7fffu + ((a.u >> 16) & 1u)) & 0xffff0000u;  // RN to bf16
    hi = (unsigned short)(r >> 16);
    union { float f; unsigned int u; } d; d.f = x - __uint_as_float(r);
    lo = (unsigned short)(d.u >> 16);  // truncation of residual
}

// C[i][j] = f * sum_k Lt[k*S1+i] * R[k*S1+j]   (C = Lt^T * R, all stride S1)
__device__ __forceinline__ void mm68(const float* __restrict__ Lt,
                                     const float* __restrict__ R,
                                     float* __restrict__ C,
                                     float f, float* __restrict__ Eacc, int tid) {
    const int i0 = (tid & 15) * 4;
    const int j0 = (tid >> 4) * 4;
    float acc[4][4];
#pragma unroll
    for (int r = 0; r < 4; ++r)
#pragma unroll
        for (int c = 0; c < 4; ++c) acc[r][c] = 0.f;

#pragma unroll 8
    for (int k = 0; k < 64; ++k) {
        const float4 a = *reinterpret_cast<const float4*>(&Lt[k * S1 + i0]);
        const float4 b = *reinterpret_cast<const float4*>(&R[k * S1 + j0]);
        const float av[4] = {a.x, a.y, a.z, a.w};
        const float bv[4] = {b.x, b.y, b.z, b.w};
#pragma unroll
        for (int r = 0; r < 4; ++r)
#pragma unroll
            for (int c = 0; c < 4; ++c) acc[r][c] = fmaf(av[r], bv[c], acc[r][c]);
    }

#pragma unroll
    for (int r = 0; r < 4; ++r) {
        float4 v;
        v.x = acc[r][0] * f; v.y = acc[r][1] * f; v.z = acc[r][2] * f; v.w = acc[r][3] * f;
        *reinterpret_cast<float4*>(&C[(i0 + r) * S1 + j0]) = v;
        if (Eacc) {
            float* e = &Eacc[(i0 + r) * S1 + j0];
            e[0] += v.x; e[1] += v.y; e[2] += v.z; e[3] += v.w;
        }
    }
}

__device__ __forceinline__ void transpose68(const float* __restrict__ X,
                                            float* __restrict__ XT, int tid) {
    const int i = tid >> 2;
    const int j0 = (tid & 3) * 16;
#pragma unroll
    for (int c4 = 0; c4 < 4; ++c4) {
        const float4 v = *reinterpret_cast<const float4*>(&X[i * S1 + j0 + 4 * c4]);
        XT[(j0 + 4 * c4 + 0) * S1 + i] = v.x;
        XT[(j0 + 4 * c4 + 1) * S1 + i] = v.y;
        XT[(j0 + 4 * c4 + 2) * S1 + i] = v.z;
        XT[(j0 + 4 * c4 + 3) * S1 + i] = v.w;
    }
}

__global__ __launch_bounds__(256)
void expm_traj(const float* __restrict__ K, const float* __restrict__ tim,
               const float* __restrict__ inputs, float* __restrict__ out) {
    __shared__ float As[64 * S1];
    __shared__ float Pa[64 * S1];
    __shared__ float Pb[64 * S1];
    __shared__ float Et[64 * S1];
    __shared__ float Tx[64 * S1];
    __shared__ float red[64];

    const int tid = threadIdx.x;
    const int t = blockIdx.x;
    const float tval = tim[t];

    // ---- Phase A: expm(K * tval) -> cur (row-major [i][j], stride S1) ----
    if (tid < 64) {
        float s = 0.f;
        for (int j = 0; j < 64; ++j) s += fabsf(K[tid * 64 + j]);
        red[tid] = s;
    }
    __syncthreads();
    if (tid == 0) {
        float m = 0.f;
        for (int i = 0; i < 64; ++i) m = fmaxf(m, red[i]);
        const float nt = m * tval;
        int s = 0;
        if (nt > THETA) {
            s = (int)ceilf(log2f(nt / THETA));
            if (s < 0) s = 0;
        }
        red[0] = ldexpf(tval, -s);
        red[1] = (float)s;
    }
    __syncthreads();
    const float scale = red[0];
    const int sq = (int)red[1];
    __syncthreads();

    // As = K*scale ; Pa = As^T (=P1^T) ; Et = I^T + As^T
    {
        const int i = tid >> 2;
        const int j0 = (tid & 3) * 16;
#pragma unroll
        for (int c = 0; c < 16; ++c) {
            const int j = j0 + c;
            const float v = K[i * 64 + j] * scale;
            As[i * S1 + j] = v;
            Pa[j * S1 + i] = v;
            Et[j * S1 + i] = v + ((i == j) ? 1.f : 0.f);
        }
    }
    __syncthreads();

    float* Pcur = Pa;
    float* Pnext = Pb;
    for (int n = 2; n <= MTERMS; ++n) {
        mm68(As, Pcur, Pnext, 1.0f / (float)n, Et, tid);
        __syncthreads();
        float* tmp = Pcur; Pcur = Pnext; Pnext = tmp;
    }

    transpose68(Et, Tx, tid);     // Tx = E (row-major [i][j])
    __syncthreads();
    float* cur = Tx;
    float* nxt = Pa;
    const float* curT = Et;
    for (int r = 0; r < sq; ++r) {
        if (r > 0) {
            transpose68(cur, Pb, tid);
            __syncthreads();
            curT = Pb;
        }
        mm68(curT, cur, nxt, 1.f, nullptr, tid);
        __syncthreads();
        float* tmp = cur; cur = nxt; nxt = tmp;
    }
    // cur = mats[t], all threads see it after the last __syncthreads above.

    // ---- Phase B: traj. mats fragments -> registers (bf16 hi/lo split) ----
    const int w  = tid >> 6;        // wave id
    const int l  = tid & 63;
    const int ln = l & 15;
    const int qd = l >> 4;          // 0..3

    // MFMA A-operand (mats): row i = m*16+ln, k = kh*32 + qd*8
    short8 Mh[4][2], Ml[4][2];
#pragma unroll
    for (int m = 0; m < 4; ++m)
#pragma unroll
        for (int kh = 0; kh < 2; ++kh) {
            const float* src = &cur[(m * 16 + ln) * S1 + kh * 32 + qd * 8];
            const float4 v0 = *reinterpret_cast<const float4*>(src);
            const float4 v1 = *reinterpret_cast<const float4*>(src + 4);
            unsigned short h[8], lo[8];
            bf16_split(v0.x, h[0], lo[0]); bf16_split(v0.y, h[1], lo[1]);
            bf16_split(v0.z, h[2], lo[2]); bf16_split(v0.w, h[3], lo[3]);
            bf16_split(v1.x, h[4], lo[4]); bf16_split(v1.y, h[5], lo[5]);
            bf16_split(v1.z, h[6], lo[6]); bf16_split(v1.w, h[7], lo[7]);
            short8 sh, sl;
#pragma unroll
            for (int e = 0; e < 8; ++e) { sh[e] = (short)h[e]; sl[e] = (short)lo[e]; }
            Mh[m][kh] = sh; Ml[m][kh] = sl;
        }

    // Stream all 4096 b-rows for this t. Wave w handles rows it*64 + w*16 + ln.
    for (int it = 0; it < 64; ++it) {
        const int brow = it * 64 + w * 16 + ln;

        // x0 fragment (MFMA B-operand): col b = ln, k = kh*32 + qd*8,
        // loaded fp32 from inputs[brow][0][:] and split in-register.
        short8 Xh[2], Xl[2];
#pragma unroll
        for (int kh = 0; kh < 2; ++kh) {
            const float* src = inputs + (size_t)brow * (TT * DD) + kh * 32 + qd * 8;
            const float4 v0 = *reinterpret_cast<const float4*>(src);
            const float4 v1 = *reinterpret_cast<const float4*>(src + 4);
            unsigned short h[8], lo[8];
            bf16_split(v0.x, h[0], lo[0]); bf16_split(v0.y, h[1], lo[1]);
            bf16_split(v0.z, h[2], lo[2]); bf16_split(v0.w, h[3], lo[3]);
            bf16_split(v1.x, h[4], lo[4]); bf16_split(v1.y, h[5], lo[5]);
            bf16_split(v1.z, h[6], lo[6]); bf16_split(v1.w, h[7], lo[7]);
            short8 sh, sl;
#pragma unroll
            for (int e = 0; e < 8; ++e) { sh[e] = (short)h[e]; sl[e] = (short)lo[e]; }
            Xh[kh] = sh; Xl[kh] = sl;
        }

        f32x4 acc[4];
#pragma unroll
        for (int m = 0; m < 4; ++m) acc[m] = (f32x4){0.f, 0.f, 0.f, 0.f};

#pragma unroll
        for (int kh = 0; kh < 2; ++kh)
#pragma unroll
            for (int m = 0; m < 4; ++m) {
                acc[m] = __builtin_amdgcn_mfma_f32_16x16x32_bf16(Mh[m][kh], Xh[kh], acc[m], 0, 0, 0);
                acc[m] = __builtin_amdgcn_mfma_f32_16x16x32_bf16(Ml[m][kh], Xh[kh], acc[m], 0, 0, 0);
                acc[m] = __builtin_amdgcn_mfma_f32_16x16x32_bf16(Mh[m][kh], Xl[kh], acc[m], 0, 0, 0);
            }

        // out[brow][t][m*16 + qd*4 + r] = acc[m][r] -> one float4 per m
        float* obase = out + (size_t)brow * (TT * DD) + (size_t)t * DD + qd * 4;
#pragma unroll
        for (int m = 0; m < 4; ++m) {
            float4 v;
            v.x = acc[m][0]; v.y = acc[m][1]; v.z = acc[m][2]; v.w = acc[m][3];
            *reinterpret_cast<float4*>(obase + m * 16) = v;
        }
    }
}

extern "C" void kernel_launch(void* const* d_in, const int* in_sizes, int n_in,
                              void* d_out, int out_size, void* d_ws, size_t ws_size,
                              hipStream_t stream) {
    const float* inputs = (const float*)d_in[0];
    const float* tim    = (const float*)d_in[1];
    const float* K      = (const float*)d_in[2];
    float* out = (float*)d_out;
    (void)d_ws; (void)ws_size;

    expm_traj<<<TT, 256, 0, stream>>>(K, tim, inputs, out);
}